// Round 8
// baseline (173.944 us; speedup 1.0000x reference)
//
#include <hip/hip_runtime.h>

// B=32, H=W=128, C_IN=C_OUT=32, 3x3 SAME conv, per-sample hypernet weights
// Wk[b] = (P[b] @ dense_w).reshape(3,3,32,32).
//
// R13 = R12 fixed: flat-VGPR-address global_load (the SGPR-base asm form
// mis-allocated). Direct-global conv with asm load pipeline + counted vmcnt.
//  - R8/R9/R10: hipcc sinks C++ reg prefetches (VGPR 108/84/64) -> 81-86us.
//  - R11 (LDS-staged): latency-bound at 8 waves/CU: 41us, 2.5TB/s, Mfma 8%.
//  - Here: R10 geometry (FETCH 33MB; L2/L3 serve 3x row reuse; 12 waves/CU),
//    loads = asm volatile global_load_dwordx4 v,v[2],off (can't sink),
//    waits = counted s_waitcnt vmcnt(N) + sched_barrier(0) (rule #18).
//    vmcnt ledger accounts for the 8 C++ Y-stores/tile, valid for either
//    placement of stores within their wait-bounded window:
//      t=0: 12/12/12; t=1..6: 20/20/12; t=7: 20/14/0.
//  - B-frags in 18.4KB LDS; "memory"-clobbered waits stop LDS-read hoisting
//    (no 72-VGPR bf pressure). (256,3): 170-VGPR budget, no spill of the
//    asm-tied L[72] (spill of un-awaited asm dest = silent corruption).

#define BATCH 32
#define HDIM 128
#define WDIM 128
#define CIN 32
#define COUT 32
#define PDIM 128
#define KCOLS 9216  // 3*3*32*32

typedef _Float16 f16x8 __attribute__((ext_vector_type(8)));
typedef float f32x4 __attribute__((ext_vector_type(4)));

__device__ __forceinline__ f16x8 zero8() {
    f16x8 z;
#pragma unroll
    for (int j = 0; j < 8; ++j) z[j] = (_Float16)0.f;
    return z;
}

__device__ __forceinline__ f16x8 cvt8(f32x4 lo, f32x4 hi) {
    f16x8 o;
#pragma unroll
    for (int j = 0; j < 4; ++j) {
        o[j] = (_Float16)lo[j];
        o[4 + j] = (_Float16)hi[j];
    }
    return o;
}

// ---------------------------------------------------------------------------
// hyper_gemm: A = P @ dense_w -> f16, swizzled to MFMA B-frag layout
// WB[b][((kc*2 + co>>4)*64 + (ci>>3)*16 + (co&15))*8 + (ci&7)].
// 288 blocks x 256 thr (verified R8-R11). Dw col-panel read twice (L3-served).
// ---------------------------------------------------------------------------
__global__ __launch_bounds__(256) void hyper_gemm(const float* __restrict__ P,
                                                  const float* __restrict__ Dw,
                                                  unsigned short* __restrict__ WB) {
    const int tid = threadIdx.x;
    const int lane = tid & 63;
    const int cg = blockIdx.x % 144;
    const int bq = blockIdx.x / 144;  // 0..1
    const int col = cg * 64 + lane;
    const int b0 = __builtin_amdgcn_readfirstlane(bq * 16 + (tid >> 6) * 4);
    const float* pb = P + (size_t)b0 * PDIM;  // wave-uniform base -> s_load

    float acc[4];
#pragma unroll
    for (int j = 0; j < 4; ++j) acc[j] = 0.f;

#pragma unroll 2
    for (int mm = 0; mm < PDIM; mm += 16) {
        float d[16];
#pragma unroll
        for (int u = 0; u < 16; ++u) d[u] = Dw[(size_t)(mm + u) * KCOLS + col];
#pragma unroll
        for (int u = 0; u < 16; ++u) {
#pragma unroll
            for (int j = 0; j < 4; ++j) acc[j] += d[u] * pb[j * PDIM + mm + u];
        }
    }

    const int co = col & 31;
    const int k = col >> 5;
    const int kc = k >> 5;
    const int ci = k & 31;
    const int base =
        ((kc * 2 + (co >> 4)) * 64 + (ci >> 3) * 16 + (co & 15)) * 8 + (ci & 7);
#pragma unroll
    for (int j = 0; j < 4; ++j) {
        _Float16 v = (_Float16)acc[j];
        WB[(size_t)(b0 + j) * KCOLS + base] = __builtin_bit_cast(unsigned short, v);
    }
}

// ---------------------------------------------------------------------------
// conv_asm: implicit-GEMM conv, f32 X direct from global, asm load pipeline.
// Grid 1024 (XCD-swizzled), 256 thr / 4 waves, wave = one output row,
// 8 tiles of 16 px. Per-lane 64-bit addresses A[kh][kw] (+2048B per tile);
// t0/kw0 clamp via separate A00, t7/kw2 clamp via -128 on m16==15.
// ---------------------------------------------------------------------------

#define GLOAD0(dst, a64)                          \
    asm volatile("global_load_dwordx4 %0, %1, off" \
                 : "=v"(dst)                       \
                 : "v"(a64))
#define GLOAD16(dst, a64)                                    \
    asm volatile("global_load_dwordx4 %0, %1, off offset:16" \
                 : "=v"(dst)                                 \
                 : "v"(a64))

#define WAITK(N)                                                  \
    do {                                                          \
        asm volatile("s_waitcnt vmcnt(" #N ")" ::: "memory");     \
        __builtin_amdgcn_sched_barrier(0);                        \
    } while (0)

// Issue trio (TT, KH) into slot S. A holds tile-TT addresses at issue time.
#define ISSUE_T(S, TT, KH)                                                   \
    {                                                                        \
        const unsigned long long a0 = ((TT) == 0) ? A00[KH] : A[KH][0];      \
        const unsigned long long a2 =                                        \
            A[KH][2] - (((TT) == 7 && m16 == 15) ? 128ull : 0ull);           \
        GLOAD0(L[S][0][0], a0);                                              \
        GLOAD16(L[S][0][1], a0);                                             \
        GLOAD0(L[S][1][0], A[KH][1]);                                        \
        GLOAD16(L[S][1][1], A[KH][1]);                                       \
        GLOAD0(L[S][2][0], a2);                                              \
        GLOAD16(L[S][2][1], a2);                                             \
    }

#define CONSUME(S, TT, KH, VALID)                                                                           \
    if (VALID) {                                                                                            \
        f16x8 a0 = cvt8(L[S][0][0], L[S][0][1]);                                                            \
        f16x8 a1 = cvt8(L[S][1][0], L[S][1][1]);                                                            \
        f16x8 a2 = cvt8(L[S][2][0], L[S][2][1]);                                                            \
        if ((TT) == 0 && m16 == 0) a0 = zero8();                                                            \
        if ((TT) == 7 && m16 == 15) a2 = zero8();                                                           \
        acc0 = __builtin_amdgcn_mfma_f32_16x16x32_f16(a0, bfl[(((KH)*3 + 0) * 2 + 0) * 64], acc0, 0, 0, 0); \
        acc1 = __builtin_amdgcn_mfma_f32_16x16x32_f16(a0, bfl[(((KH)*3 + 0) * 2 + 1) * 64], acc1, 0, 0, 0); \
        acc0 = __builtin_amdgcn_mfma_f32_16x16x32_f16(a1, bfl[(((KH)*3 + 1) * 2 + 0) * 64], acc0, 0, 0, 0); \
        acc1 = __builtin_amdgcn_mfma_f32_16x16x32_f16(a1, bfl[(((KH)*3 + 1) * 2 + 1) * 64], acc1, 0, 0, 0); \
        acc0 = __builtin_amdgcn_mfma_f32_16x16x32_f16(a2, bfl[(((KH)*3 + 2) * 2 + 0) * 64], acc0, 0, 0, 0); \
        acc1 = __builtin_amdgcn_mfma_f32_16x16x32_f16(a2, bfl[(((KH)*3 + 2) * 2 + 1) * 64], acc1, 0, 0, 0); \
    }

__global__ __launch_bounds__(256, 3) void conv_asm(const float* __restrict__ X,
                                                   const unsigned short* __restrict__ WB,
                                                   float* __restrict__ Y) {
    __shared__ f16x8 BFs[KCOLS / 8];  // 18432 B: frag i at [i*64 + lane]
    const int tid = threadIdx.x;

    // XCD-aware swizzle: 1024 % 8 == 0 -> simple bijective form.
    const int wg = blockIdx.x;
    const int id = (wg & 7) * 128 + (wg >> 3);
    const int b = id >> 5;   // image
    const int hg = id & 31;  // 4-row group
    const int waveu = __builtin_amdgcn_readfirstlane(tid >> 6);  // scalar
    const int lane = tid & 63;
    const int q = lane >> 4;       // ci octet
    const int m16 = lane & 15;     // pixel within tile
    const int h = hg * 4 + waveu;  // scalar

    // ---- stage B-frag table to LDS (1152 x 16B, coalesced, L2-hot) ----
    {
        const f16x8* wbp = (const f16x8*)(WB + (size_t)b * KCOLS);
        for (int i = tid; i < KCOLS / 8; i += 256) BFs[i] = wbp[i];
    }
    __syncthreads();  // compiler drains staging vmcnt -> counter starts at 0

    const bool v0 = (h > 0);         // wave-uniform
    const bool v2 = (h < HDIM - 1);  // wave-uniform
    const float* xb = X + (size_t)b * HDIM * WDIM * CIN;
    const float* rp0 = xb + (size_t)(v0 ? h - 1 : 0) * WDIM * CIN;
    const float* rp1 = xb + (size_t)h * WDIM * CIN;
    const float* rp2 = xb + (size_t)(v2 ? h + 1 : 0) * WDIM * CIN;

    // per-lane byte offsets within a row for the 3 kw taps (tile 0 values)
    const int off0 = (m16 - 1) * 128 + q * 32;  // never issued at t=0
    const int off1 = m16 * 128 + q * 32;
    const int off2 = (m16 + 1) * 128 + q * 32;
    const int off00 = (m16 == 0 ? 0 : (m16 - 1) * 128) + q * 32;  // t0 clamp

    unsigned long long A[3][3];  // [kh][kw], compile-time indexed after unroll
    unsigned long long A00[3];
    {
        const unsigned long long r0u = (unsigned long long)rp0;
        const unsigned long long r1u = (unsigned long long)rp1;
        const unsigned long long r2u = (unsigned long long)rp2;
        A[0][0] = r0u + off0; A[0][1] = r0u + off1; A[0][2] = r0u + off2;
        A[1][0] = r1u + off0; A[1][1] = r1u + off1; A[1][2] = r1u + off2;
        A[2][0] = r2u + off0; A[2][1] = r2u + off1; A[2][2] = r2u + off2;
        A00[0] = r0u + off00; A00[1] = r1u + off00; A00[2] = r2u + off00;
    }

    const f16x8* bfl = BFs + lane;
    f32x4 L[3][3][2];  // slot = kh; all indices compile-time after unroll

    float* ybase = Y + (((size_t)b * HDIM + h) * WDIM + q * 4) * COUT + m16;

    // prologue: trios (0,0) and (0,1)  -> 12 outstanding
    ISSUE_T(0, 0, 0);
    ISSUE_T(1, 0, 1);

#pragma unroll
    for (int t = 0; t < 8; ++t) {
        f32x4 acc0 = {0.f, 0.f, 0.f, 0.f};
        f32x4 acc1 = {0.f, 0.f, 0.f, 0.f};

        // step (t,0): issue trio(t,2); consume trio(t,0)
        ISSUE_T(2, t, 2);
        if (t < 7) {  // advance all 9 addresses to tile t+1 (fills wait shadow)
#pragma unroll
            for (int kh = 0; kh < 3; ++kh)
#pragma unroll
                for (int kw = 0; kw < 3; ++kw) A[kh][kw] += 2048ull;
        }
        if (t == 0) WAITK(12); else WAITK(20);
        CONSUME(0, t, 0, v0);

        // step (t,1): issue trio(t+1,0); consume trio(t,1)
        if (t == 0) {
            ISSUE_T(0, 1, 0);
            WAITK(12);
        } else if (t < 7) {
            ISSUE_T(0, t + 1, 0);
            WAITK(20);
        } else {
            WAITK(14);
        }
        CONSUME(1, t, 1, true);

        // step (t,2): issue trio(t+1,1); consume trio(t,2)
        if (t == 0) {
            ISSUE_T(1, 1, 1);
            WAITK(12);
        } else if (t < 7) {
            ISSUE_T(1, t + 1, 1);
            WAITK(12);
        } else {
            WAITK(0);
        }
        CONSUME(2, t, 2, v2);

        // D layout: col = lane&15 (co), row = q*4 + r (pixel). Plain stores:
        // acc0+acc1 halves of each 128B line merge in L2. Stores are bounded
        // by the "memory"-clobbered waits; ledger covers either placement.
        float* yp = ybase + t * 16 * COUT;
#pragma unroll
        for (int r = 0; r < 4; ++r) {
            yp[r * COUT] = acc0[r];
            yp[r * COUT + 16] = acc1[r];
        }
    }
}

extern "C" void kernel_launch(void* const* d_in, const int* in_sizes, int n_in,
                              void* d_out, int out_size, void* d_ws, size_t ws_size,
                              hipStream_t stream) {
    const float* X = (const float*)d_in[0];   // [32,128,128,32]
    const float* P = (const float*)d_in[1];   // [32,128]
    const float* Dw = (const float*)d_in[2];  // [128,9216]
    float* Y = (float*)d_out;                 // [32,128,128,32]
    (void)ws_size;

    unsigned short* WB = (unsigned short*)d_ws;  // 589824 B

    hipLaunchKernelGGL(hyper_gemm, dim3(288), dim3(256), 0, stream, P, Dw, WB);
    hipLaunchKernelGGL(conv_asm, dim3(1024), dim3(256), 0, stream, X, WB, Y);
}

// Round 9
// 146.721 us; speedup vs baseline: 1.1855x; 1.1855x over previous
//
#include <hip/hip_runtime.h>

// B=32, H=W=128, C_IN=C_OUT=32, 3x3 SAME conv, per-sample hypernet weights
// Wk[b] = (P[b] @ dense_w).reshape(3,3,32,32).
//
// R14: many short blocks (4-row), 3 blocks/CU -> phase pipelining.
//  R9-R13 post-mortem: hipcc will not hold a register load-pipeline on this
//  shape (MachineSinking R9/R10, allocator spill of asm-tied regs R13:
//  VGPR=60 < 72 live slots). The LDS-staged family (R7 44.7us, R11 41.1us)
//  is phase-serialization bound: engines sum ~45% busy, blocks lockstep
//  through read-burst|barrier|compute+write-burst. FIX: shrink blocks 4x
//  (4 rows, 256 thr, LDS 50KB = X 32KB + BF 18.4KB) -> 3 blocks/CU, grid
//  1024; block retirement pipelines stage(n+1) under compute(n) on each CU.
//  All inner math byte-identical to the verified R7/R8/R11 lineage.

#define BATCH 32
#define HDIM 128
#define WDIM 128
#define CIN 32
#define COUT 32
#define PDIM 128
#define KCOLS 9216  // 3*3*32*32

typedef _Float16 f16x8 __attribute__((ext_vector_type(8)));
typedef float f32x4 __attribute__((ext_vector_type(4)));

__device__ __forceinline__ f16x8 zero8() {
    f16x8 z;
#pragma unroll
    for (int j = 0; j < 8; ++j) z[j] = (_Float16)0.f;
    return z;
}

__device__ __forceinline__ f16x8 cvt8(f32x4 lo, f32x4 hi) {
    f16x8 o;
#pragma unroll
    for (int j = 0; j < 4; ++j) {
        o[j] = (_Float16)lo[j];
        o[4 + j] = (_Float16)hi[j];
    }
    return o;
}

// ---------------------------------------------------------------------------
// hyper_gemm: A = P @ dense_w -> f16, swizzled to MFMA B-frag layout
// WB[b][((kc*2 + co>>4)*64 + (ci>>3)*16 + (co&15))*8 + (ci&7)].
// 288 blocks x 256 thr (verified R8-R13). Dw col-panel read twice (L3-served).
// ---------------------------------------------------------------------------
__global__ __launch_bounds__(256) void hyper_gemm(const float* __restrict__ P,
                                                  const float* __restrict__ Dw,
                                                  unsigned short* __restrict__ WB) {
    const int tid = threadIdx.x;
    const int lane = tid & 63;
    const int cg = blockIdx.x % 144;
    const int bq = blockIdx.x / 144;  // 0..1
    const int col = cg * 64 + lane;
    const int b0 = __builtin_amdgcn_readfirstlane(bq * 16 + (tid >> 6) * 4);
    const float* pb = P + (size_t)b0 * PDIM;  // wave-uniform base -> s_load

    float acc[4];
#pragma unroll
    for (int j = 0; j < 4; ++j) acc[j] = 0.f;

#pragma unroll 2
    for (int mm = 0; mm < PDIM; mm += 16) {
        float d[16];
#pragma unroll
        for (int u = 0; u < 16; ++u) d[u] = Dw[(size_t)(mm + u) * KCOLS + col];
#pragma unroll
        for (int u = 0; u < 16; ++u) {
#pragma unroll
            for (int j = 0; j < 4; ++j) acc[j] += d[u] * pb[j * PDIM + mm + u];
        }
    }

    const int co = col & 31;
    const int k = col >> 5;
    const int kc = k >> 5;
    const int ci = k & 31;
    const int base =
        ((kc * 2 + (co >> 4)) * 64 + (ci >> 3) * 16 + (co & 15)) * 8 + (ci & 7);
#pragma unroll
    for (int j = 0; j < 4; ++j) {
        _Float16 v = (_Float16)acc[j];
        WB[(size_t)(b0 + j) * KCOLS + base] = __builtin_bit_cast(unsigned short, v);
    }
}

// ---------------------------------------------------------------------------
// conv_s4: implicit-GEMM conv, 4-row LDS-staged blocks.
// Grid 1024 (XCD-swizzled: image-local on one XCD), block = 256 thr /
// 4 waves, wave = one output row, 8 tiles of 16 px.
// LDS: Xs 32 KB = [4 rows][128 px][4 x 16B slots], slot = q ^ (px>>1)
//      (verified R7/R8/R11); BFs 18.4 KB (frag i at [i*64 + lane]).
// Total 50 KB -> 3 blocks/CU (12 waves). Short stage phase (16 loads/thr)
// -> block retirement pipelines read/compute/write streams across blocks.
// Halo: wave0 kh=0 / wave3 kh=2 from f32 global with 1-tile prefetch.
// ---------------------------------------------------------------------------
__device__ __forceinline__ f16x8 halo_ld(const f32x4* __restrict__ gp, int px) {
    const bool ok = (unsigned)px < 128u;
    const int p = ok ? px : 0;
    f32x4 lo = gp[p * 8];
    f32x4 hi = gp[p * 8 + 1];
    f16x8 o = cvt8(lo, hi);
    if (!ok) o = zero8();
    return o;
}

__global__ __launch_bounds__(256, 3) void conv_s4(const float* __restrict__ X,
                                                  const unsigned short* __restrict__ WB,
                                                  float* __restrict__ Y) {
    __shared__ f16x8 Xs[4 * 512];     // 32 KB: [row 0..3][px*4 + slot]
    __shared__ f16x8 BFs[KCOLS / 8];  // 18432 B: frag i at [i*64 + lane]
    const int tid = threadIdx.x;

    // XCD-aware swizzle: 1024 % 8 == 0 -> simple bijective form.
    const int wg = blockIdx.x;
    const int id = (wg & 7) * 128 + (wg >> 3);
    const int b = id >> 5;   // image
    const int hg = id & 31;  // 4-row group
    const int r0 = hg * 4;

    const int wave = tid >> 6;
    const int lane = tid & 63;
    const int q = lane >> 4;    // ci octet
    const int m16 = lane & 15;  // pixel within tile

    // ---- stage B-frag table to LDS (1152 x 16B, coalesced, L2-hot) ----
    {
        const f16x8* wbp = (const f16x8*)(WB + (size_t)b * KCOLS);
#pragma unroll
        for (int i = 0; i < 5; ++i) {
            const int idx = tid + i * 256;
            if (idx < KCOLS / 8) BFs[idx] = wbp[idx];
        }
    }

    // ---- stage 4 rows: f32 load -> f16 -> swizzled LDS (2 octets/thr/row) --
    {
        const int px_s = tid >> 1;       // 0..127
        const int qb = (tid & 1) * 2;    // octet pair base
#pragma unroll
        for (int r = 0; r < 4; ++r) {
#pragma unroll
            for (int p = 0; p < 2; ++p) {
                const int q_s = qb + p;
                const float* src =
                    X + (((size_t)b * HDIM + r0 + r) * WDIM + px_s) * CIN + q_s * 8;
                f32x4 lo = *(const f32x4*)src;
                f32x4 hi = *(const f32x4*)(src + 4);
                const int g_s = px_s * 4 + ((q_s ^ (px_s >> 1)) & 3);
                Xs[r * 512 + g_s] = cvt8(lo, hi);
            }
        }
    }
    __syncthreads();

    // ---- halo setup (waves 0 and 3 only) ----
    const bool top = (wave == 0);
    const bool bot = (wave == 3);
    const bool gvalid = top ? (hg != 0) : (bot ? (hg != 31) : false);
    const int grow = top ? (hg ? r0 - 1 : 0) : (r0 + 4);
    const f32x4* gp = (const f32x4*)X +
                      ((size_t)b * HDIM + (gvalid ? grow : 0)) * (WDIM * CIN / 4) +
                      q * 2;

    f16x8 hal[3];
    if (gvalid) {
#pragma unroll
        for (int kw = 0; kw < 3; ++kw) hal[kw] = halo_ld(gp, m16 + kw - 1);
    } else {
#pragma unroll
        for (int kw = 0; kw < 3; ++kw) hal[kw] = zero8();
    }

    // ---- per-lane LDS byte offsets, base row (wave-1); +kh*8192 at use ----
    int va[3];
#pragma unroll
    for (int kw = 0; kw < 3; ++kw) {
        const int px = m16 + kw - 1;
        const int sl = (q ^ (px >> 1)) & 3;
        va[kw] = (wave - 1) * 8192 + px * 64 + sl * 16;
    }

    const char* xsb = (const char*)Xs;
    const f16x8* bfl = BFs + lane;
    const int h = r0 + wave;
    float* ybase = Y + (((size_t)b * HDIM + h) * WDIM + q * 4) * COUT + m16;

#pragma unroll
    for (int t = 0; t < 8; ++t) {
        f32x4 acc0 = {0.f, 0.f, 0.f, 0.f};
        f32x4 acc1 = {0.f, 0.f, 0.f, 0.f};

#pragma unroll
        for (int kh = 0; kh < 3; ++kh) {
            f16x8 a0, a1, a2;
            const bool use_lds =
                (kh == 1) || (kh == 0 && wave != 0) || (kh == 2 && wave != 3);
            if (use_lds) {
                int v0 = va[0] + kh * 8192;
                int v1 = va[1] + kh * 8192;
                int v2 = va[2] + kh * 8192;
                if (t == 0) v0 += (m16 == 0) ? 64 : 0;   // px=-1 -> safe slot
                if (t == 7) v2 -= (m16 == 15) ? 64 : 0;  // px=128 -> safe slot
                a0 = *(const f16x8*)(xsb + v0);
                a1 = *(const f16x8*)(xsb + v1);
                a2 = *(const f16x8*)(xsb + v2);
                if (t == 0 && m16 == 0) a0 = zero8();
                if (t == 7 && m16 == 15) a2 = zero8();
            } else {
                a0 = hal[0];
                a1 = hal[1];
                a2 = hal[2];
                if (gvalid && t < 7) {  // prefetch next tile's halo trio
#pragma unroll
                    for (int kw = 0; kw < 3; ++kw)
                        hal[kw] = halo_ld(gp, (t + 1) * 16 + m16 + kw - 1);
                }
            }
            acc0 = __builtin_amdgcn_mfma_f32_16x16x32_f16(a0, bfl[((kh * 3 + 0) * 2 + 0) * 64], acc0, 0, 0, 0);
            acc1 = __builtin_amdgcn_mfma_f32_16x16x32_f16(a0, bfl[((kh * 3 + 0) * 2 + 1) * 64], acc1, 0, 0, 0);
            acc0 = __builtin_amdgcn_mfma_f32_16x16x32_f16(a1, bfl[((kh * 3 + 1) * 2 + 0) * 64], acc0, 0, 0, 0);
            acc1 = __builtin_amdgcn_mfma_f32_16x16x32_f16(a1, bfl[((kh * 3 + 1) * 2 + 1) * 64], acc1, 0, 0, 0);
            acc0 = __builtin_amdgcn_mfma_f32_16x16x32_f16(a2, bfl[((kh * 3 + 2) * 2 + 0) * 64], acc0, 0, 0, 0);
            acc1 = __builtin_amdgcn_mfma_f32_16x16x32_f16(a2, bfl[((kh * 3 + 2) * 2 + 1) * 64], acc1, 0, 0, 0);
        }

        // D layout: col = lane&15 (co), row = q*4 + r (pixel). Plain stores:
        // acc0+acc1 halves of each 128B line merge in L2.
        float* yp = ybase + t * 16 * COUT;
#pragma unroll
        for (int r = 0; r < 4; ++r) {
            yp[r * COUT] = acc0[r];
            yp[r * COUT + 16] = acc1[r];
        }

#pragma unroll
        for (int kw = 0; kw < 3; ++kw) va[kw] += 1024;  // +16 px
    }
}

extern "C" void kernel_launch(void* const* d_in, const int* in_sizes, int n_in,
                              void* d_out, int out_size, void* d_ws, size_t ws_size,
                              hipStream_t stream) {
    const float* X = (const float*)d_in[0];   // [32,128,128,32]
    const float* P = (const float*)d_in[1];   // [32,128]
    const float* Dw = (const float*)d_in[2];  // [128,9216]
    float* Y = (float*)d_out;                 // [32,128,128,32]
    (void)ws_size;

    unsigned short* WB = (unsigned short*)d_ws;  // 589824 B

    hipLaunchKernelGGL(hyper_gemm, dim3(288), dim3(256), 0, stream, P, Dw, WB);
    hipLaunchKernelGGL(conv_s4, dim3(1024), dim3(256), 0, stream, X, WB, Y);
}

// Round 10
// 141.409 us; speedup vs baseline: 1.2301x; 1.0376x over previous
//
#include <hip/hip_runtime.h>

// B=32, H=W=128, C_IN=C_OUT=32, 3x3 SAME conv, per-sample hypernet weights
// Wk[b] = (P[b] @ dense_w).reshape(3,3,32,32).
//
// R15: 32x32x16 MFMA (halved per-pixel instruction count).
//  R7-R14 bracket a 41-51us conv plateau with ALL engines <=30% busy ->
//  issue/instruction-bound at 16x16 granularity: per 16px tile 27 ds_read
//  + 18 MFMA + 8 stores. With mfma_f32_32x32x16_f16 a 32px x 32co tile is
//  2 MFMAs/tap: per 32px = 36 ds_read + 18 MFMA (vs 54+36). Same bytes,
//  same verified LDS swizzle (bank-uniform for the 32-wide read; checked).
//  Fragment maps (gfx950 family pattern): A m=lane&31,k=(lane>>5)*8+j;
//  B n=lane&31,k=(lane>>5)*8+j (hyper swizzle updated); D col=lane&31,
//  row=(reg&3)+8*(reg>>2)+4*(lane>>5) (HW-verified mapping).
//  Structure = R14: 1024 blocks x 256 thr / 4 waves, wave = 1 row,
//  Xs 32KB + BFs 18.4KB = 50KB -> 3 blocks/CU.

#define BATCH 32
#define HDIM 128
#define WDIM 128
#define CIN 32
#define COUT 32
#define PDIM 128
#define KCOLS 9216  // 3*3*32*32

typedef _Float16 f16x8 __attribute__((ext_vector_type(8)));
typedef float f32x4 __attribute__((ext_vector_type(4)));
typedef float f32x16 __attribute__((ext_vector_type(16)));

__device__ __forceinline__ f16x8 zero8() {
    f16x8 z;
#pragma unroll
    for (int j = 0; j < 8; ++j) z[j] = (_Float16)0.f;
    return z;
}

__device__ __forceinline__ f16x8 cvt8(f32x4 lo, f32x4 hi) {
    f16x8 o;
#pragma unroll
    for (int j = 0; j < 4; ++j) {
        o[j] = (_Float16)lo[j];
        o[4 + j] = (_Float16)hi[j];
    }
    return o;
}

// ---------------------------------------------------------------------------
// hyper_gemm: A = P @ dense_w -> f16, swizzled to 32x32x16 B-frag layout.
// Frag f = kc*2 + (ci>>4); lane = ((ci>>3)&1)*32 + co; j = ci&7.
// WB[b][(f*64 + lane)*8 + j]. 288 blocks x 256 thr (structure verified
// R8-R14; only the swizzle formula changes).
// ---------------------------------------------------------------------------
__global__ __launch_bounds__(256) void hyper_gemm(const float* __restrict__ P,
                                                  const float* __restrict__ Dw,
                                                  unsigned short* __restrict__ WB) {
    const int tid = threadIdx.x;
    const int lane = tid & 63;
    const int cg = blockIdx.x % 144;
    const int bq = blockIdx.x / 144;  // 0..1
    const int col = cg * 64 + lane;
    const int b0 = __builtin_amdgcn_readfirstlane(bq * 16 + (tid >> 6) * 4);
    const float* pb = P + (size_t)b0 * PDIM;  // wave-uniform base -> s_load

    float acc[4];
#pragma unroll
    for (int j = 0; j < 4; ++j) acc[j] = 0.f;

#pragma unroll 2
    for (int mm = 0; mm < PDIM; mm += 16) {
        float d[16];
#pragma unroll
        for (int u = 0; u < 16; ++u) d[u] = Dw[(size_t)(mm + u) * KCOLS + col];
#pragma unroll
        for (int u = 0; u < 16; ++u) {
#pragma unroll
            for (int j = 0; j < 4; ++j) acc[j] += d[u] * pb[j * PDIM + mm + u];
        }
    }

    const int co = col & 31;
    const int k = col >> 5;
    const int kc = k >> 5;   // tap 0..8
    const int ci = k & 31;   // input channel
    const int base =
        ((kc * 2 + (ci >> 4)) * 64 + ((ci >> 3) & 1) * 32 + co) * 8 + (ci & 7);
#pragma unroll
    for (int j = 0; j < 4; ++j) {
        _Float16 v = (_Float16)acc[j];
        WB[(size_t)(b0 + j) * KCOLS + base] = __builtin_bit_cast(unsigned short, v);
    }
}

// ---------------------------------------------------------------------------
// conv_w32: implicit-GEMM conv, 32x32x16 MFMA, 4-row LDS-staged blocks.
// Grid 1024 (XCD-swizzled), 256 thr / 4 waves, wave = one row, 4 tiles of
// 32 px. Per tile per tap (kh,kw): 2 A ds_read_b128 + 2 B ds_read + 2 MFMA.
// Xs 32 KB = [4 rows][128 px][4 x 16B slots], slot = octet ^ (px>>1) (R7-R14
// verified); BFs 18.4 KB. Halo: wave0 kh=0 / wave3 kh=2 from f32 global
// with 1-tile prefetch (OOB px self-zeroing).
// ---------------------------------------------------------------------------
__device__ __forceinline__ f16x8 halo_ld32(const f32x4* __restrict__ gp, int px,
                                           int oct) {
    const bool ok = (unsigned)px < 128u;
    const int p = ok ? px : 0;
    f32x4 lo = gp[p * 8 + oct * 2];
    f32x4 hi = gp[p * 8 + oct * 2 + 1];
    f16x8 o = cvt8(lo, hi);
    if (!ok) o = zero8();
    return o;
}

__global__ __launch_bounds__(256, 3) void conv_w32(const float* __restrict__ X,
                                                   const unsigned short* __restrict__ WB,
                                                   float* __restrict__ Y) {
    __shared__ f16x8 Xs[4 * 512];     // 32 KB: [row 0..3][px*4 + slot]
    __shared__ f16x8 BFs[KCOLS / 8];  // 18432 B: frag f at [f*64 + lane]
    const int tid = threadIdx.x;

    // XCD-aware swizzle: 1024 % 8 == 0 -> simple bijective form.
    const int wg = blockIdx.x;
    const int id = (wg & 7) * 128 + (wg >> 3);
    const int b = id >> 5;   // image
    const int hg = id & 31;  // 4-row group
    const int r0 = hg * 4;

    const int wave = tid >> 6;
    const int lane = tid & 63;
    const int m32 = lane & 31;  // pixel within 32-px tile
    const int hi = lane >> 5;   // k-octet selector

    // ---- stage B-frag table to LDS (1152 x 16B, coalesced, L2-hot) ----
    {
        const f16x8* wbp = (const f16x8*)(WB + (size_t)b * KCOLS);
#pragma unroll
        for (int i = 0; i < 5; ++i) {
            const int idx = tid + i * 256;
            if (idx < KCOLS / 8) BFs[idx] = wbp[idx];
        }
    }

    // ---- stage 4 rows: f32 load -> f16 -> swizzled LDS (R14-verified) ----
    {
        const int px_s = tid >> 1;     // 0..127
        const int qb = (tid & 1) * 2;  // octet pair base
#pragma unroll
        for (int r = 0; r < 4; ++r) {
#pragma unroll
            for (int p = 0; p < 2; ++p) {
                const int q_s = qb + p;
                const float* src =
                    X + (((size_t)b * HDIM + r0 + r) * WDIM + px_s) * CIN + q_s * 8;
                f32x4 lo = *(const f32x4*)src;
                f32x4 hi4 = *(const f32x4*)(src + 4);
                const int g_s = px_s * 4 + ((q_s ^ (px_s >> 1)) & 3);
                Xs[r * 512 + g_s] = cvt8(lo, hi4);
            }
        }
    }
    __syncthreads();

    // ---- halo setup (waves 0 and 3 only) ----
    const bool top = (wave == 0);
    const bool bot = (wave == 3);
    const bool gvalid = top ? (hg != 0) : (bot ? (hg != 31) : false);
    const int grow = top ? (hg ? r0 - 1 : 0) : (r0 + 4);
    const f32x4* gp = (const f32x4*)X +
                      ((size_t)b * HDIM + (gvalid ? grow : 0)) * (WDIM * CIN / 4);

    // hal[kw][h]: halo A-frags for current tile; octet = 2h + hi.
    f16x8 hal[3][2];
    if (gvalid) {
#pragma unroll
        for (int kw = 0; kw < 3; ++kw)
#pragma unroll
            for (int h = 0; h < 2; ++h)
                hal[kw][h] = halo_ld32(gp, m32 + kw - 1, 2 * h + hi);
    } else {
#pragma unroll
        for (int kw = 0; kw < 3; ++kw)
#pragma unroll
            for (int h = 0; h < 2; ++h) hal[kw][h] = zero8();
    }

    // ---- per-lane LDS byte offsets within a row slab, tile 0 ----
    // slot' = (2h+hi) ^ ((px>>1)&3); invariant under px += 32.
    int o0[2], o1[2], o2[2], o00[2];
    {
        const int p0 = m32 - 1, p1 = m32, p2 = m32 + 1;
#pragma unroll
        for (int h = 0; h < 2; ++h) {
            const int s = 2 * h + hi;
            o0[h] = p0 * 64 + ((s ^ ((p0 >> 1) & 3)) & 3) * 16;  // p0=-1 ok: addr only used t>=1
            o1[h] = p1 * 64 + ((s ^ ((p1 >> 1) & 3)) & 3) * 16;
            o2[h] = p2 * 64 + ((s ^ ((p2 >> 1) & 3)) & 3) * 16;
            const int pc = (m32 == 0) ? 0 : p0;  // t=0 clamp
            o00[h] = pc * 64 + ((s ^ ((pc >> 1) & 3)) & 3) * 16;
        }
    }

    const char* xsb = (const char*)Xs;
    const f16x8* bfl = BFs + lane;
    const int h_out = r0 + wave;
    const int co = m32;
    // D: col(co)=lane&31, row(px)=(r&3)+8*(r>>2)+4*hi within the 32-px tile.
    float* ybase = Y + (((size_t)b * HDIM + h_out) * WDIM) * COUT + co;

#pragma unroll
    for (int t = 0; t < 4; ++t) {
        f32x16 acc = {};

#pragma unroll
        for (int kh = 0; kh < 3; ++kh) {
            f16x8 a[3][2];
            const bool use_lds =
                (kh == 1) || (kh == 0 && wave != 0) || (kh == 2 && wave != 3);
            if (use_lds) {
                const int ro = (wave - 1 + kh) * 8192;
#pragma unroll
                for (int h = 0; h < 2; ++h) {
                    const int ad0 =
                        ro + ((t == 0) ? o00[h] : (o0[h] + t * 2048));
                    const int ad1 = ro + o1[h] + t * 2048;
                    const int ad2 = ro + o2[h] + t * 2048 -
                                    ((t == 3 && m32 == 31) ? 64 : 0);
                    a[0][h] = *(const f16x8*)(xsb + ad0);
                    a[1][h] = *(const f16x8*)(xsb + ad1);
                    a[2][h] = *(const f16x8*)(xsb + ad2);
                }
                if (t == 0 && m32 == 0) { a[0][0] = zero8(); a[0][1] = zero8(); }
                if (t == 3 && m32 == 31) { a[2][0] = zero8(); a[2][1] = zero8(); }
            } else {
#pragma unroll
                for (int kw = 0; kw < 3; ++kw)
#pragma unroll
                    for (int h = 0; h < 2; ++h) a[kw][h] = hal[kw][h];
                if (gvalid && t < 3) {  // prefetch next tile (OOB self-zeroing)
#pragma unroll
                    for (int kw = 0; kw < 3; ++kw)
#pragma unroll
                        for (int h = 0; h < 2; ++h)
                            hal[kw][h] = halo_ld32(gp, (t + 1) * 32 + m32 + kw - 1,
                                                   2 * h + hi);
                }
            }
#pragma unroll
            for (int kw = 0; kw < 3; ++kw) {
#pragma unroll
                for (int h = 0; h < 2; ++h) {
                    acc = __builtin_amdgcn_mfma_f32_32x32x16_f16(
                        a[kw][h], bfl[(((kh * 3 + kw) * 2) + h) * 64], acc, 0, 0, 0);
                }
            }
        }

        // store: px = t*32 + (r&3) + 8*(r>>2) + 4*hi; co = lane&31.
        float* yp = ybase + (size_t)(t * 32 + 4 * hi) * COUT;
#pragma unroll
        for (int r2 = 0; r2 < 4; ++r2) {
#pragma unroll
            for (int r1 = 0; r1 < 4; ++r1) {
                yp[(size_t)(r1 + 8 * r2) * COUT] = acc[r2 * 4 + r1];
            }
        }
    }
}

extern "C" void kernel_launch(void* const* d_in, const int* in_sizes, int n_in,
                              void* d_out, int out_size, void* d_ws, size_t ws_size,
                              hipStream_t stream) {
    const float* X = (const float*)d_in[0];   // [32,128,128,32]
    const float* P = (const float*)d_in[1];   // [32,128]
    const float* Dw = (const float*)d_in[2];  // [128,9216]
    float* Y = (float*)d_out;                 // [32,128,128,32]
    (void)ws_size;

    unsigned short* WB = (unsigned short*)d_ws;  // 589824 B

    hipLaunchKernelGGL(hyper_gemm, dim3(288), dim3(256), 0, stream, P, Dw, WB);
    hipLaunchKernelGGL(conv_w32, dim3(1024), dim3(256), 0, stream, X, WB, Y);
}

// Round 12
// 139.730 us; speedup vs baseline: 1.2449x; 1.0120x over previous
//
#include <hip/hip_runtime.h>

// B=32, H=W=128, C_IN=C_OUT=32, 3x3 SAME conv, per-sample hypernet weights
// Wk[b] = (P[b] @ dense_w).reshape(3,3,32,32).
//
// R17 = R16 resubmitted (R11-round infra failure: "container failed twice"
// with no compile/test output; same broker failure as R1, which passed
// unchanged on resubmit. Source re-audited: launch bounds legal, LDS offsets
// bounded, barriers non-divergent, no graph-capture violations.)
//
// R16 thesis: R7-R15 plateau (41-51us) with every engine <=30% busy and
// Occupancy 15-18% => latency-bound, too few waves (12/CU; VGPR 68 caps at
// 16/CU per m69's 64/128/256 occupancy steps). FIX: same 4-row/50.4KB-LDS
// tile but 512 thr / 8 waves (wave = HALF row, 4 tiles of 16px) +
// launch_bounds(512,8) pinning VGPR=64 -> 3 blocks/CU x 8 = 24 waves/CU
// (2x R14) and halved per-wave dependency chains. 16x16 MFMA math + hyper
// swizzle = R14-verified (R15's 32x32 layout reverted: 983K bank conflicts).

#define BATCH 32
#define HDIM 128
#define WDIM 128
#define CIN 32
#define COUT 32
#define PDIM 128
#define KCOLS 9216  // 3*3*32*32

typedef _Float16 f16x8 __attribute__((ext_vector_type(8)));
typedef float f32x4 __attribute__((ext_vector_type(4)));

__device__ __forceinline__ f16x8 zero8() {
    f16x8 z;
#pragma unroll
    for (int j = 0; j < 8; ++j) z[j] = (_Float16)0.f;
    return z;
}

__device__ __forceinline__ f16x8 cvt8(f32x4 lo, f32x4 hi) {
    f16x8 o;
#pragma unroll
    for (int j = 0; j < 4; ++j) {
        o[j] = (_Float16)lo[j];
        o[4 + j] = (_Float16)hi[j];
    }
    return o;
}

// ---------------------------------------------------------------------------
// hyper_gemm: A = P @ dense_w -> f16, swizzled to 16x16x32 MFMA B-frag layout
// WB[b][((kc*2 + co>>4)*64 + (ci>>3)*16 + (co&15))*8 + (ci&7)]  (R8-R14).
// 288 blocks x 256 thr. Dw col-panel read twice (L3-served).
// ---------------------------------------------------------------------------
__global__ __launch_bounds__(256) void hyper_gemm(const float* __restrict__ P,
                                                  const float* __restrict__ Dw,
                                                  unsigned short* __restrict__ WB) {
    const int tid = threadIdx.x;
    const int lane = tid & 63;
    const int cg = blockIdx.x % 144;
    const int bq = blockIdx.x / 144;  // 0..1
    const int col = cg * 64 + lane;
    const int b0 = __builtin_amdgcn_readfirstlane(bq * 16 + (tid >> 6) * 4);
    const float* pb = P + (size_t)b0 * PDIM;  // wave-uniform base -> s_load

    float acc[4];
#pragma unroll
    for (int j = 0; j < 4; ++j) acc[j] = 0.f;

#pragma unroll 2
    for (int mm = 0; mm < PDIM; mm += 16) {
        float d[16];
#pragma unroll
        for (int u = 0; u < 16; ++u) d[u] = Dw[(size_t)(mm + u) * KCOLS + col];
#pragma unroll
        for (int u = 0; u < 16; ++u) {
#pragma unroll
            for (int j = 0; j < 4; ++j) acc[j] += d[u] * pb[j * PDIM + mm + u];
        }
    }

    const int co = col & 31;
    const int k = col >> 5;
    const int kc = k >> 5;
    const int ci = k & 31;
    const int base =
        ((kc * 2 + (co >> 4)) * 64 + (ci >> 3) * 16 + (co & 15)) * 8 + (ci & 7);
#pragma unroll
    for (int j = 0; j < 4; ++j) {
        _Float16 v = (_Float16)acc[j];
        WB[(size_t)(b0 + j) * KCOLS + base] = __builtin_bit_cast(unsigned short, v);
    }
}

// ---------------------------------------------------------------------------
// conv_tlp: implicit-GEMM conv, 4-row blocks, 8 half-row waves.
// Grid 1024 (XCD-swizzled), block = 512 thr / 8 waves. Wave w: row = w>>1,
// half = w&1, tiles t = half*4 + tt (tt=0..3), 16 px each.
// LDS: Xs 32 KB [4 rows][128 px][4 x 16B slots], slot = q ^ (px>>1)
//      (R7-R14 verified); BFs 18.4 KB. Total 50.4 KB -> 3 blocks/CU.
// launch_bounds(512,8): VGPR pinned to 64 -> 24 waves/CU resident.
// Halo: row 0 (waves 0,1) kh=0 / row 3 (waves 6,7) kh=2 from f32 global
// with 1-tile prefetch over the wave's own px half-range.
// ---------------------------------------------------------------------------
__device__ __forceinline__ f16x8 halo_ld(const f32x4* __restrict__ gp, int px) {
    const bool ok = (unsigned)px < 128u;
    const int p = ok ? px : 0;
    f32x4 lo = gp[p * 8];
    f32x4 hi = gp[p * 8 + 1];
    f16x8 o = cvt8(lo, hi);
    if (!ok) o = zero8();
    return o;
}

__global__ __launch_bounds__(512, 8) void conv_tlp(const float* __restrict__ X,
                                                   const unsigned short* __restrict__ WB,
                                                   float* __restrict__ Y) {
    __shared__ f16x8 Xs[4 * 512];     // 32 KB: [row 0..3][px*4 + slot]
    __shared__ f16x8 BFs[KCOLS / 8];  // 18432 B: frag i at [i*64 + lane]
    const int tid = threadIdx.x;

    // XCD-aware swizzle: 1024 % 8 == 0 -> simple bijective form.
    const int wg = blockIdx.x;
    const int id = (wg & 7) * 128 + (wg >> 3);
    const int b = id >> 5;   // image
    const int hg = id & 31;  // 4-row group
    const int r0 = hg * 4;

    const int wave = tid >> 6;
    const int row = wave >> 1;   // 0..3
    const int half = wave & 1;   // half-row selector
    const int lane = tid & 63;
    const int q = lane >> 4;     // ci octet
    const int m16 = lane & 15;   // pixel within tile
    const int t0 = half * 4;     // first tile of this wave

    // ---- stage B-frag table to LDS (1152 x 16B, coalesced, L2-hot) ----
    {
        const f16x8* wbp = (const f16x8*)(WB + (size_t)b * KCOLS);
        for (int i = tid; i < KCOLS / 8; i += 512) BFs[i] = wbp[i];
    }

    // ---- stage 4 rows: f32 load -> f16 -> swizzled LDS (1 octet/thr/row) --
    {
        const int px_s = tid >> 2;     // 0..127
        const int q_s = tid & 3;       // octet
        const int g_s = px_s * 4 + ((q_s ^ (px_s >> 1)) & 3);
#pragma unroll
        for (int r = 0; r < 4; ++r) {
            const float* src =
                X + (((size_t)b * HDIM + r0 + r) * WDIM + px_s) * CIN + q_s * 8;
            f32x4 lo = *(const f32x4*)src;
            f32x4 hi = *(const f32x4*)(src + 4);
            Xs[r * 512 + g_s] = cvt8(lo, hi);
        }
    }
    __syncthreads();

    // ---- halo setup (rows 0 and 3 only) ----
    const bool top = (row == 0);
    const bool bot = (row == 3);
    const bool gvalid = top ? (hg != 0) : (bot ? (hg != 31) : false);
    const int grow = top ? (hg ? r0 - 1 : 0) : (r0 + 4);
    const f32x4* gp = (const f32x4*)X +
                      ((size_t)b * HDIM + (gvalid ? grow : 0)) * (WDIM * CIN / 4) +
                      q * 2;

    f16x8 hal[3];
    if (gvalid) {
#pragma unroll
        for (int kw = 0; kw < 3; ++kw)
            hal[kw] = halo_ld(gp, t0 * 16 + m16 + kw - 1);
    } else {
#pragma unroll
        for (int kw = 0; kw < 3; ++kw) hal[kw] = zero8();
    }

    // ---- per-lane LDS byte offsets at tile t0, base row (row-1) ----
    // sl = (q ^ (px>>1))&3 is invariant under px += 16 (and px=-1 ~ 15 ok).
    int va[3];
#pragma unroll
    for (int kw = 0; kw < 3; ++kw) {
        const int px = t0 * 16 + m16 + kw - 1;
        const int sl = (q ^ (px >> 1)) & 3;
        va[kw] = (row - 1) * 8192 + px * 64 + sl * 16;
    }

    const char* xsb = (const char*)Xs;
    const f16x8* bfl = BFs + lane;
    const int h = r0 + row;
    float* ybase = Y + (((size_t)b * HDIM + h) * WDIM + q * 4) * COUT + m16;

#pragma unroll
    for (int tt = 0; tt < 4; ++tt) {
        const int t = t0 + tt;  // 0..7 global tile index
        f32x4 acc0 = {0.f, 0.f, 0.f, 0.f};
        f32x4 acc1 = {0.f, 0.f, 0.f, 0.f};

#pragma unroll
        for (int kh = 0; kh < 3; ++kh) {
            f16x8 a0, a1, a2;
            const bool use_lds =
                (kh == 1) || (kh == 0 && row != 0) || (kh == 2 && row != 3);
            if (use_lds) {
                int v0 = va[0] + kh * 8192;
                int v1 = va[1] + kh * 8192;
                int v2 = va[2] + kh * 8192;
                if (half == 0 && tt == 0) v0 += (m16 == 0) ? 64 : 0;   // px=-1
                if (half == 1 && tt == 3) v2 -= (m16 == 15) ? 64 : 0;  // px=128
                a0 = *(const f16x8*)(xsb + v0);
                a1 = *(const f16x8*)(xsb + v1);
                a2 = *(const f16x8*)(xsb + v2);
                if (half == 0 && tt == 0 && m16 == 0) a0 = zero8();
                if (half == 1 && tt == 3 && m16 == 15) a2 = zero8();
            } else {
                a0 = hal[0];
                a1 = hal[1];
                a2 = hal[2];
                if (gvalid && tt < 3) {  // prefetch next tile's halo trio
#pragma unroll
                    for (int kw = 0; kw < 3; ++kw)
                        hal[kw] = halo_ld(gp, (t + 1) * 16 + m16 + kw - 1);
                }
            }
            acc0 = __builtin_amdgcn_mfma_f32_16x16x32_f16(a0, bfl[((kh * 3 + 0) * 2 + 0) * 64], acc0, 0, 0, 0);
            acc1 = __builtin_amdgcn_mfma_f32_16x16x32_f16(a0, bfl[((kh * 3 + 0) * 2 + 1) * 64], acc1, 0, 0, 0);
            acc0 = __builtin_amdgcn_mfma_f32_16x16x32_f16(a1, bfl[((kh * 3 + 1) * 2 + 0) * 64], acc0, 0, 0, 0);
            acc1 = __builtin_amdgcn_mfma_f32_16x16x32_f16(a1, bfl[((kh * 3 + 1) * 2 + 1) * 64], acc1, 0, 0, 0);
            acc0 = __builtin_amdgcn_mfma_f32_16x16x32_f16(a2, bfl[((kh * 3 + 2) * 2 + 0) * 64], acc0, 0, 0, 0);
            acc1 = __builtin_amdgcn_mfma_f32_16x16x32_f16(a2, bfl[((kh * 3 + 2) * 2 + 1) * 64], acc1, 0, 0, 0);
        }

        // D layout: col = lane&15 (co), row = q*4 + r (pixel). Plain stores:
        // acc0+acc1 halves of each 128B line merge in L2.
        float* yp = ybase + t * 16 * COUT;
#pragma unroll
        for (int r = 0; r < 4; ++r) {
            yp[r * COUT] = acc0[r];
            yp[r * COUT + 16] = acc1[r];
        }

#pragma unroll
        for (int kw = 0; kw < 3; ++kw) va[kw] += 1024;  // +16 px
    }
}

extern "C" void kernel_launch(void* const* d_in, const int* in_sizes, int n_in,
                              void* d_out, int out_size, void* d_ws, size_t ws_size,
                              hipStream_t stream) {
    const float* X = (const float*)d_in[0];   // [32,128,128,32]
    const float* P = (const float*)d_in[1];   // [32,128]
    const float* Dw = (const float*)d_in[2];  // [128,9216]
    float* Y = (float*)d_out;                 // [32,128,128,32]
    (void)ws_size;

    unsigned short* WB = (unsigned short*)d_ws;  // 589824 B

    hipLaunchKernelGGL(hyper_gemm, dim3(288), dim3(256), 0, stream, P, Dw, WB);
    hipLaunchKernelGGL(conv_tlp, dim3(1024), dim3(512), 0, stream, X, WB, Y);
}